// Round 1
// baseline (364.035 us; speedup 1.0000x reference)
//
#include <hip/hip_runtime.h>

#define NROWS 131072
#define DDIM  64
#define KCTR  512
#define OUT_W (1 + DDIM + KCTR)   /* 577 */
#define RBF_REG 1e-4f
#define KTILE 8

__global__ __launch_bounds__(256) void dicrbf_kernel(
    const float* __restrict__ data,
    const float* __restrict__ centers,
    float* __restrict__ out)
{
    __shared__ float cnorm[KCTR];

    const int t = threadIdx.x;

    // Cooperatively compute center squared norms (once per block, 2 KB LDS).
    for (int k = t; k < KCTR; k += 256) {
        const float4* c4 = reinterpret_cast<const float4*>(centers + (size_t)k * DDIM);
        float s = 0.f;
#pragma unroll
        for (int i = 0; i < DDIM / 4; ++i) {
            float4 v = c4[i];
            s += v.x * v.x + v.y * v.y + v.z * v.z + v.w * v.w;
        }
        cnorm[k] = s;
    }
    __syncthreads();

    const int row = blockIdx.x * 256 + t;
    if (row >= NROWS) return;

    // Load this thread's data row into registers (64 f32).
    const float4* x4 = reinterpret_cast<const float4*>(data + (size_t)row * DDIM);
    float4 x[DDIM / 4];
#pragma unroll
    for (int i = 0; i < DDIM / 4; ++i) x[i] = x4[i];

    float xsq = 0.f;
#pragma unroll
    for (int i = 0; i < DDIM / 4; ++i)
        xsq += x[i].x * x[i].x + x[i].y * x[i].y + x[i].z * x[i].z + x[i].w * x[i].w;

    float* orow = out + (size_t)row * OUT_W;

    // ones column + data passthrough (cols 0..64). orow+1 is only 4B-aligned,
    // so scalar stores.
    orow[0] = 1.0f;
#pragma unroll
    for (int i = 0; i < DDIM / 4; ++i) {
        orow[1 + 4 * i + 0] = x[i].x;
        orow[1 + 4 * i + 1] = x[i].y;
        orow[1 + 4 * i + 2] = x[i].z;
        orow[1 + 4 * i + 3] = x[i].w;
    }

    // Main loop: KTILE=8 accumulator chains; center reads are wave-uniform
    // (every lane reads the same address -> broadcast, ~1 transaction).
#pragma unroll 1
    for (int k0 = 0; k0 < KCTR; k0 += KTILE) {
        float acc[KTILE];
#pragma unroll
        for (int kk = 0; kk < KTILE; ++kk) acc[kk] = 0.f;

        const float4* c4 = reinterpret_cast<const float4*>(centers + (size_t)k0 * DDIM);

#pragma unroll
        for (int i = 0; i < DDIM / 4; ++i) {
            const float4 xv = x[i];
#pragma unroll
            for (int kk = 0; kk < KTILE; ++kk) {
                const float4 cv = c4[kk * (DDIM / 4) + i];
                acc[kk] += xv.x * cv.x;
                acc[kk] += xv.y * cv.y;
                acc[kk] += xv.z * cv.z;
                acc[kk] += xv.w * cv.w;
            }
        }

#pragma unroll
        for (int kk = 0; kk < KTILE; ++kk) {
            float d2 = xsq + cnorm[k0 + kk] - 2.0f * acc[kk];
            d2 = fmaxf(d2, 0.0f);
            float r = __fsqrt_rn(d2);
            float v = (d2 > 0.0f) ? d2 * __logf(r + RBF_REG) : 0.0f;
            orow[1 + DDIM + k0 + kk] = v;
        }
    }
}

extern "C" void kernel_launch(void* const* d_in, const int* in_sizes, int n_in,
                              void* d_out, int out_size, void* d_ws, size_t ws_size,
                              hipStream_t stream) {
    const float* data    = (const float*)d_in[0];
    const float* centers = (const float*)d_in[1];
    float* out = (float*)d_out;

    dim3 grid(NROWS / 256);
    dim3 block(256);
    hipLaunchKernelGGL(dicrbf_kernel, grid, block, 0, stream, data, centers, out);
}

// Round 2
// 128.405 us; speedup vs baseline: 2.8350x; 2.8350x over previous
//
#include <hip/hip_runtime.h>

#define NROWS 131072
#define DDIM  64
#define KCTR  512
#define OUT_W 577           /* 1 + 64 + 512 */
#define RBF_REG 1e-4f

typedef __attribute__((ext_vector_type(8))) short bfrag8;
typedef __attribute__((ext_vector_type(4))) float f32x4;

__device__ __forceinline__ short f2bf(float f) {
    union { float f; unsigned u; } v; v.f = f;
    return (short)((v.u + 0x8000u) >> 16);   // round-to-nearest (ties away)
}

// Prep: center squared norms (f32) + centers converted to bf16, into d_ws.
__global__ __launch_bounds__(256) void prep_kernel(
    const float* __restrict__ centers, float* __restrict__ cnorm,
    short* __restrict__ cbf)
{
    int k = blockIdx.x * 256 + threadIdx.x;
    if (k >= KCTR) return;
    const float* c = centers + (size_t)k * DDIM;
    short* o = cbf + (size_t)k * DDIM;
    float s = 0.f;
#pragma unroll
    for (int i0 = 0; i0 < DDIM; i0 += 8) {
        bfrag8 b;
#pragma unroll
        for (int j = 0; j < 8; ++j) {
            float v = c[i0 + j];
            s += v * v;
            b[j] = f2bf(v);
        }
        *reinterpret_cast<bfrag8*>(o + i0) = b;   // 16B store
    }
    cnorm[k] = s;
}

// Main: each block owns 32 rows x all 512 centers. 4 waves, each 32m x 128n
// via mfma_f32_16x16x32_bf16.
__global__ __launch_bounds__(256) void dicrbf_mfma(
    const float* __restrict__ data,
    const float* __restrict__ cnorm_g,
    const short* __restrict__ cbf,
    float* __restrict__ out)
{
    __shared__ float s_cnorm[KCTR];
    __shared__ float s_xsq[32];

    const int t = threadIdx.x;
    const int row0 = blockIdx.x * 32;

    // cnorm -> LDS
    for (int k = t; k < KCTR; k += 256) s_cnorm[k] = cnorm_g[k];

    // row squared norms (f32, exact) -> LDS
    if (t < 32) {
        const float4* x4 = reinterpret_cast<const float4*>(data + (size_t)(row0 + t) * DDIM);
        float s = 0.f;
#pragma unroll
        for (int i = 0; i < DDIM / 4; ++i) {
            float4 v = x4[i];
            s += v.x * v.x + v.y * v.y + v.z * v.z + v.w * v.w;
        }
        s_xsq[t] = s;
    }

    // ones + data passthrough: 32 rows x 65 cols, 8 threads per row
    {
        const int r = t >> 3, j = t & 7;
        const float* src = data + (size_t)(row0 + r) * DDIM + j * 8;
        float* dst = out + (size_t)(row0 + r) * OUT_W + 1 + j * 8;
#pragma unroll
        for (int i = 0; i < 8; ++i) dst[i] = src[i];
        if (j == 0) out[(size_t)(row0 + r) * OUT_W] = 1.0f;
    }
    __syncthreads();

    const int wid  = t >> 6;
    const int lane = t & 63;
    const int l15  = lane & 15;
    const int lhi  = lane >> 4;
    const int n_base = wid * 128;

    // A fragments: mf in {0,1} (row halves), ks in {0,1} (k halves of 32)
    // lane layout: row = l15, k = ks*32 + lhi*8 + j
    bfrag8 a[2][2];
#pragma unroll
    for (int mf = 0; mf < 2; ++mf) {
#pragma unroll
        for (int ks = 0; ks < 2; ++ks) {
            const float* ap = data + (size_t)(row0 + mf * 16 + l15) * DDIM + ks * 32 + lhi * 8;
            const float4 v0 = reinterpret_cast<const float4*>(ap)[0];
            const float4 v1 = reinterpret_cast<const float4*>(ap)[1];
            bfrag8 fr;
            fr[0] = f2bf(v0.x); fr[1] = f2bf(v0.y); fr[2] = f2bf(v0.z); fr[3] = f2bf(v0.w);
            fr[4] = f2bf(v1.x); fr[5] = f2bf(v1.y); fr[6] = f2bf(v1.z); fr[7] = f2bf(v1.w);
            a[mf][ks] = fr;
        }
    }

    f32x4 acc[2][8];
#pragma unroll
    for (int mf = 0; mf < 2; ++mf)
#pragma unroll
        for (int nf = 0; nf < 8; ++nf)
            acc[mf][nf] = (f32x4)(0.f);

#pragma unroll
    for (int ks = 0; ks < 2; ++ks) {
        bfrag8 b[8];
#pragma unroll
        for (int nf = 0; nf < 8; ++nf) {
            // B lane layout: col = l15, k = ks*32 + lhi*8 + j ; B[k][n] = centers[n][k]
            const short* bp = cbf + (size_t)(n_base + nf * 16 + l15) * DDIM + ks * 32 + lhi * 8;
            b[nf] = *reinterpret_cast<const bfrag8*>(bp);   // 16B load
        }
#pragma unroll
        for (int mf = 0; mf < 2; ++mf)
#pragma unroll
            for (int nf = 0; nf < 8; ++nf)
                acc[mf][nf] = __builtin_amdgcn_mfma_f32_16x16x32_bf16(
                    a[mf][ks], b[nf], acc[mf][nf], 0, 0, 0);
    }

    // Epilogue: d2 = xsq + cnorm - 2*dot ; rbf = d2*log(sqrt(d2)+reg)
    // D layout: col = l15 (center n), row = lhi*4 + reg (data row)
#pragma unroll
    for (int mf = 0; mf < 2; ++mf) {
#pragma unroll
        for (int nf = 0; nf < 8; ++nf) {
            const int n = n_base + nf * 16 + l15;
            const float cn = s_cnorm[n];
#pragma unroll
            for (int r = 0; r < 4; ++r) {
                const int rl = mf * 16 + lhi * 4 + r;
                float d2 = s_xsq[rl] + cn - 2.0f * acc[mf][nf][r];
                d2 = fmaxf(d2, 0.0f);
                const float rr = __fsqrt_rn(d2);
                float v = d2 * __logf(rr + RBF_REG);
                v = (d2 > 0.0f) ? v : 0.0f;
                out[(size_t)(row0 + rl) * OUT_W + 1 + DDIM + n] = v;
            }
        }
    }
}

extern "C" void kernel_launch(void* const* d_in, const int* in_sizes, int n_in,
                              void* d_out, int out_size, void* d_ws, size_t ws_size,
                              hipStream_t stream) {
    const float* data    = (const float*)d_in[0];
    const float* centers = (const float*)d_in[1];
    float* out = (float*)d_out;

    float* cnorm = (float*)d_ws;                     // 512 f32 = 2 KB
    short* cbf   = (short*)((char*)d_ws + 2048);     // 512*64 bf16 = 64 KB

    hipLaunchKernelGGL(prep_kernel, dim3(2), dim3(256), 0, stream, centers, cnorm, cbf);
    hipLaunchKernelGGL(dicrbf_mfma, dim3(NROWS / 32), dim3(256), 0, stream,
                       data, cnorm, cbf, out);
}